// Round 5
// baseline (516.653 us; speedup 1.0000x reference)
//
#include <hip/hip_runtime.h>
#include <cstdint>
#include <cstddef>

#define T_SEQ 2048
#define B_SZ  8
#define F_DIM 768
#define H_CNT 3
#define DH    256
#define E_ELE (T_SEQ * B_SZ * F_DIM)   // 12582912 elems per activation tensor
#define W_ELE (F_DIM * F_DIM)          // 589824 elems per weight matrix

typedef float floatx4  __attribute__((ext_vector_type(4)));
typedef float floatx16 __attribute__((ext_vector_type(16)));
typedef short bf16x8   __attribute__((ext_vector_type(8)));

// round-half-up f32->bf16 (2 VALU); ties differ from RNE by 1 ulp (noise here)
static __device__ __forceinline__ unsigned short f2bf(float f) {
    union { float f; unsigned int i; } x; x.f = f;
    return (unsigned short)((x.i + 0x8000u) >> 16);
}
// pack two f32 -> u32 of two bf16 (lo=a, hi=b): 2 adds + v_perm
static __device__ __forceinline__ unsigned int pkbf(float a, float b) {
    union { float f; unsigned int i; } xa, xb; xa.f = a; xb.f = b;
    return __builtin_amdgcn_perm(xb.i + 0x8000u, xa.i + 0x8000u, 0x07060302u);
}
// load 8 consecutive fp32, convert to bf16x8 (packed converts)
static __device__ __forceinline__ bf16x8 cvt8(const float* __restrict__ p) {
    const floatx4 a = *(const floatx4*)p;
    const floatx4 b = *(const floatx4*)(p + 4);
    union { unsigned int u[4]; bf16x8 v; } r;
    r.u[0] = pkbf(a[0], a[1]); r.u[1] = pkbf(a[2], a[3]);
    r.u[2] = pkbf(b[0], b[1]); r.u[3] = pkbf(b[2], b[3]);
    return r.v;
}

// async global->LDS, 16B per lane; LDS dest = wave-uniform base + lane*16
#define ASYNC16(g, l) __builtin_amdgcn_global_load_lds( \
    (__attribute__((address_space(1))) void*)(void*)(g), \
    (__attribute__((address_space(3))) void*)(l), 16, 0, 0)

// ---------------------------------------------------------------------------
// Bulk fp32 -> bf16 (grid-stride over 8-elem chunks)
// ---------------------------------------------------------------------------
__global__ __launch_bounds__(256) void cvt_bf16(const float* __restrict__ src,
                                                unsigned short* __restrict__ dst,
                                                int n8)
{
    for (int i = blockIdx.x * 256 + threadIdx.x; i < n8; i += gridDim.x * 256)
        *(bf16x8*)(dst + (size_t)i * 8) = cvt8(src + (size_t)i * 8);
}

// Pack Wq|Wk|Wv|Wo -> bf16 [4*768][768]; pack bq|bk|bv -> fp32[2304].
__global__ __launch_bounds__(256) void cvt_w(
    const float* __restrict__ wq, const float* __restrict__ wk,
    const float* __restrict__ wv, const float* __restrict__ wo,
    const float* __restrict__ bq, const float* __restrict__ bk,
    const float* __restrict__ bv,
    unsigned short* __restrict__ wdst, float* __restrict__ bdst)
{
    const int y = blockIdx.y;
    const float* s = (y == 0) ? wq : (y == 1) ? wk : (y == 2) ? wv : wo;
    const int i = blockIdx.x * 256 + threadIdx.x;
    *(bf16x8*)(wdst + (size_t)y * W_ELE + (size_t)i * 8) = cvt8(s + (size_t)i * 8);
    if (y < 3 && i < F_DIM / 8) {
        const float* bs = (y == 0) ? bq : (y == 1) ? bk : bv;
        *(floatx4*)(bdst + y * F_DIM + i * 8)     = *(const floatx4*)(bs + i * 8);
        *(floatx4*)(bdst + y * F_DIM + i * 8 + 4) = *(const floatx4*)(bs + i * 8 + 4);
    }
}

// ---------------------------------------------------------------------------
// NT GEMM, both operands bf16, both staged via global_load_lds w16 (m97
// structure). C = (A[M,K] * W[N,K]^T + bias) [* scale].
// XCD swizzle (T1): group same-row-panel blocks onto one XCD so the A-panel
// is fetched by one L2 instead of all 8. Requires gridDim.y == 128.
// CMODE 2: C fp32 row-major.
// CMODE 5: fused QKV epilogue, 32-wide MFMA fragment layouts (see attn).
// ---------------------------------------------------------------------------
template<int CMODE>
__global__ __launch_bounds__(256, 3) void gemm_nt(
    const unsigned short* __restrict__ A,
    const unsigned short* __restrict__ W,
    const float* __restrict__ bias,
    void* __restrict__ Cv,
    int M, int N, int K, float qscale)
{
    __shared__ __align__(16) unsigned short As[128 * 32];
    __shared__ __align__(16) unsigned short Bs[128 * 32];

    const int tid  = threadIdx.x;
    const int wave = tid >> 6;
    const int lane = tid & 63;

    // XCD-aware remap: lid%8 = XCD (round-robin dispatch); each XCD owns 16
    // consecutive row-panels, x-major within.
    const int gx  = gridDim.x;
    const int lid = blockIdx.x + gx * blockIdx.y;
    const int xcd = lid & 7, kk = lid >> 3;
    const int m0 = (xcd * 16 + kk / gx) * 128;
    const int n0 = (kk % gx) * 128;

    const int wm = (wave >> 1) * 64;
    const int wn = (wave & 1) * 64;
    const int q4 = lane >> 4;
    const int rr = lane & 15;

    const int lrow = lane >> 2;        // row within 16-row chunk
    const int lk8  = (lane & 3) * 8;   // k-element offset
    const int ar0 = wave * 16 + lrow;
    const int ar1 = (wave + 4) * 16 + lrow;

    floatx4 acc[4][4];
#pragma unroll
    for (int i = 0; i < 4; ++i)
#pragma unroll
        for (int j = 0; j < 4; ++j) acc[i][j] = (floatx4)0.0f;

    for (int k0 = 0; k0 < K; k0 += 32) {
        __syncthreads();   // previous iteration's fragment reads complete
        ASYNC16(A + (size_t)(m0 + ar0) * K + k0 + lk8, (unsigned short*)As + wave * 512);
        ASYNC16(A + (size_t)(m0 + ar1) * K + k0 + lk8, (unsigned short*)As + (wave + 4) * 512);
        ASYNC16(W + (size_t)(n0 + ar0) * K + k0 + lk8, (unsigned short*)Bs + wave * 512);
        ASYNC16(W + (size_t)(n0 + ar1) * K + k0 + lk8, (unsigned short*)Bs + (wave + 4) * 512);
        __syncthreads();   // staging visible (drains vmcnt)

        bf16x8 af[4], bfv[4];
#pragma unroll
        for (int mt = 0; mt < 4; ++mt)
            af[mt] = *(const bf16x8*)&As[(wm + mt * 16 + rr) * 32 + q4 * 8];
#pragma unroll
        for (int nt = 0; nt < 4; ++nt)
            bfv[nt] = *(const bf16x8*)&Bs[(wn + nt * 16 + rr) * 32 + q4 * 8];
#pragma unroll
        for (int mt = 0; mt < 4; ++mt)
#pragma unroll
            for (int nt = 0; nt < 4; ++nt)
                acc[mt][nt] = __builtin_amdgcn_mfma_f32_16x16x32_bf16(af[mt], bfv[nt], acc[mt][nt], 0, 0, 0);
    }

#pragma unroll
    for (int nt = 0; nt < 4; ++nt) {
        const int col = n0 + wn + nt * 16 + rr;
        const float bv = bias[col];
        if (CMODE == 2) {
            float* C = (float*)Cv;
#pragma unroll
            for (int mt = 0; mt < 4; ++mt)
#pragma unroll
                for (int r = 0; r < 4; ++r) {
                    const int row = m0 + wm + mt * 16 + q4 * 4 + r;
                    C[(size_t)row * N + col] = acc[mt][nt][r] + bv;
                }
        } else {  // CMODE 5: fused QKV scatter (32-wide fragment layouts)
            const int mat = col / 768;           // wave-uniform per nt
            const int cl  = col - mat * 768;
            const int h = cl >> 8, d = cl & 255;
            const float sc = (mat == 0) ? qscale : 1.0f;
            unsigned short* base = (unsigned short*)Cv + (size_t)mat * E_ELE;
#pragma unroll
            for (int mt = 0; mt < 4; ++mt) {
#pragma unroll
                for (int r = 0; r < 4; ++r) {
                    const int row = m0 + wm + mt * 16 + q4 * 4 + r;
                    const float v = (acc[mt][nt][r] + bv) * sc;
                    const int t = row >> 3, bb = row & 7;   // row = t*B + b
                    const size_t hb = (size_t)(bb * H_CNT + h) * (T_SEQ * DH);
                    size_t idx;
                    if (mat < 2) {   // Q/K 32-wide fragment layout
                        const int tb = t >> 5, t5 = t & 31;
                        const int kc = d >> 4, hi2 = (d >> 3) & 1, e = d & 7;
                        idx = hb + (size_t)((((tb * 16 + kc) * 64 + hi2 * 32 + t5) * 8) + e);
                    } else {         // V 32-wide fragment layout
                        const int cb = t >> 5, sc2 = (t >> 4) & 1, hi2 = (t >> 3) & 1, e = t & 7;
                        const int db = d >> 5, d5 = d & 31;
                        idx = hb + (size_t)(cb * 8192 + (((db * 2 + sc2) * 64 + hi2 * 32 + d5) * 8) + e);
                    }
                    base[idx] = f2bf(v);
                }
            }
        }
    }
}

// ---------------------------------------------------------------------------
// Flash attention, barrier-free: grid (T/64, B*H), 128 threads (2 waves),
// 32 Q rows/wave, 32x32x16 MFMA. K/V fragment layouts in global memory are
// per-lane contiguous, so fragments load DIRECTLY global->VGPR (coalesced
// 16B/lane) -- no LDS staging, no __syncthreads, no vmcnt(0) drain. Only LDS
// use is the tiny per-wave P tile (wave-private => barrier-free). Latency is
// hidden by 8 loads in flight + free-running waves (6/CU).
// XCD swizzle: all 32 q-blocks of one (b,h) -> one XCD, sequential-window
// grouped, so each XCD L2 streams one 2MB K/V working set at a time.
// Raw s_barrier (no memory drain) paces the 2 waves for L1 sharing.
// ---------------------------------------------------------------------------
__global__ __launch_bounds__(128, 2) void attn_kernel(
    const unsigned short* __restrict__ Qf,
    const unsigned short* __restrict__ Kf,
    const unsigned short* __restrict__ Vf,
    unsigned short* __restrict__ Ob)
{
    __shared__ __align__(16) unsigned short Ps[2][32 * 40]; // per-wave P[q][s]

    const int tid  = threadIdx.x;
    const int wave = tid >> 6;
    const int lane = tid & 63;
    const int l31  = lane & 31;
    const int hi   = lane >> 5;

    // XCD swizzle: lid%8 = XCD; each XCD gets bh in {xcd, xcd+8, xcd+16},
    // with the 32 q-blocks of one bh consecutive (one K/V stream at a time).
    const int lid = blockIdx.x + 32 * blockIdx.y;
    const int xcd = lid & 7, kslot = lid >> 3;
    const int qx  = kslot & 31;
    const int bh  = xcd + 8 * (kslot >> 5);

    const int b  = bh / H_CNT;
    const int h  = bh % H_CNT;
    const size_t hb = (size_t)bh * (T_SEQ * DH);

    // wave's 32 Q rows = q-block qb (Q prescaled by 1/8 in the GEMM).
    const int qb = qx * 2 + wave;
    bf16x8 qf_[16];
#pragma unroll
    for (int kc = 0; kc < 16; ++kc)
        qf_[kc] = *(const bf16x8*)(Qf + hb + ((size_t)(qb * 16 + kc) * 64 + lane) * 8);

    float m_ = -1e9f, l_ = 0.0f;
    floatx16 oacc[8];   // O^T: db-tile d=db*32+row, q=l31
#pragma unroll
    for (int db = 0; db < 8; ++db) oacc[db] = (floatx16)0.0f;

    for (int s0 = 0; s0 < T_SEQ; s0 += 32) {
        const unsigned short* kg = Kf + hb + (size_t)(s0 >> 5) * 8192;
        const unsigned short* vg = Vf + hb + (size_t)(s0 >> 5) * 8192;

        // S^T = K Q^T : D[s][q] 32x32; K A-frags direct from global.
        // Two half-batches of 8 keeps peak VGPR pressure bounded.
        floatx16 sacc = (floatx16)0.0f;
#pragma unroll
        for (int half = 0; half < 2; ++half) {
            bf16x8 kf[8];
#pragma unroll
            for (int j = 0; j < 8; ++j)
                kf[j] = *(const bf16x8*)(kg + ((size_t)((half * 8 + j) * 64 + lane)) * 8);
#pragma unroll
            for (int j = 0; j < 8; ++j)
                sacc = __builtin_amdgcn_mfma_f32_32x32x16_bf16(kf[j], qf_[half * 8 + j], sacc, 0, 0, 0);
        }

        // online softmax: lane's q = l31; 16 s-values in regs, partner lane^32
        float cm = sacc[0];
#pragma unroll
        for (int r = 1; r < 16; ++r) cm = fmaxf(cm, sacc[r]);
        cm = fmaxf(cm, __shfl_xor(cm, 32));
        const float mn = fmaxf(m_, cm);
        const float alpha = __expf(m_ - mn);
        float rs = 0.0f;
#pragma unroll
        for (int r = 0; r < 16; ++r) {
            const float p = __expf(sacc[r] - mn);
            sacc[r] = p; rs += p;
        }
        rs += __shfl_xor(rs, 32);
        l_ = alpha * l_ + rs;
        const int upd = (mn > m_);
        m_ = mn;

        // P -> per-wave LDS tile P[q][s]: reg 4g+i = s = 8g + 4*hi + i
        unsigned short* pw = Ps[wave];
#pragma unroll
        for (int g = 0; g < 4; ++g) {
            const int sp = g * 8 + hi * 4;
            *(unsigned int*)&pw[l31 * 40 + sp]     = pkbf(sacc[4 * g],     sacc[4 * g + 1]);
            *(unsigned int*)&pw[l31 * 40 + sp + 2] = pkbf(sacc[4 * g + 2], sacc[4 * g + 3]);
        }
        // B-frag of P: lane holds q=l31, s = sc*16 + hi*8 + j
        const bf16x8 pf0 = *(const bf16x8*)&pw[l31 * 40 + hi * 8];
        const bf16x8 pf1 = *(const bf16x8*)&pw[l31 * 40 + 16 + hi * 8];

        // O rescale only when some row-max moved (wave-uniform skip)
        if (__any(upd)) {
#pragma unroll
            for (int db = 0; db < 8; ++db)
#pragma unroll
                for (int r = 0; r < 16; ++r) oacc[db][r] *= alpha;
        }

        // O^T += V^T P : V^T A-frags direct from global (row=d, k=s)
#pragma unroll
        for (int db = 0; db < 8; ++db) {
            const bf16x8 v0 = *(const bf16x8*)(vg + ((size_t)((db * 2 + 0) * 64 + lane)) * 8);
            const bf16x8 v1 = *(const bf16x8*)(vg + ((size_t)((db * 2 + 1) * 64 + lane)) * 8);
            oacc[db] = __builtin_amdgcn_mfma_f32_32x32x16_bf16(v0, pf0, oacc[db], 0, 0, 0);
            oacc[db] = __builtin_amdgcn_mfma_f32_32x32x16_bf16(v1, pf1, oacc[db], 0, 0, 0);
        }

        __builtin_amdgcn_s_barrier();   // pacing only (no memory drain): keeps
                                        // the 2 waves lockstep for L1 sharing
    }

    // epilogue: lane holds O[d = db*32 + 8g + 4*hi + i][q = l31]; pack pairs
    const float inv_l = 1.0f / fmaxf(l_, 1e-30f);
    const int t = qx * 64 + wave * 32 + l31;
    unsigned short* orow = Ob + (size_t)(t * B_SZ + b) * F_DIM + h * DH;
#pragma unroll
    for (int db = 0; db < 8; ++db) {
#pragma unroll
        for (int g = 0; g < 4; ++g) {
            const int d0 = db * 32 + g * 8 + hi * 4;
            *(unsigned int*)(orow + d0)     = pkbf(oacc[db][4 * g] * inv_l,
                                                   oacc[db][4 * g + 1] * inv_l);
            *(unsigned int*)(orow + d0 + 2) = pkbf(oacc[db][4 * g + 2] * inv_l,
                                                   oacc[db][4 * g + 3] * inv_l);
        }
    }
}

// ---------------------------------------------------------------------------
extern "C" void kernel_launch(void* const* d_in, const int* in_sizes, int n_in,
                              void* d_out, int out_size, void* d_ws, size_t ws_size,
                              hipStream_t stream)
{
    const float* x  = (const float*)d_in[0];
    const float* Wq = (const float*)d_in[1];
    const float* bq = (const float*)d_in[2];
    const float* Wk = (const float*)d_in[3];
    const float* bk = (const float*)d_in[4];
    const float* Wv = (const float*)d_in[5];
    const float* bv = (const float*)d_in[6];
    const float* Wo = (const float*)d_in[7];
    const float* bo = (const float*)d_in[8];
    float* out = (float*)d_out;

    const int M = T_SEQ * B_SZ;   // 16384

    // workspace: Qf | Kb | Vb | Ob(=x_bf16 before attn) | Wpack | bqkv
    unsigned short* Qf = (unsigned short*)d_ws;
    unsigned short* Kb = Qf + (size_t)E_ELE;
    unsigned short* Vb = Kb + (size_t)E_ELE;
    unsigned short* Ob = Vb + (size_t)E_ELE;      // aliases x_bf16 (dead by attn)
    unsigned short* Wp = Ob + (size_t)E_ELE;      // [Wq;Wk;Wv;Wo] bf16
    float* bqkv = (float*)(Wp + (size_t)4 * W_ELE);
    unsigned short* xb = Ob;

    cvt_bf16<<<2048, 256, 0, stream>>>(x, xb, E_ELE / 8);
    cvt_w<<<dim3(W_ELE / 8 / 256, 4), 256, 0, stream>>>(Wq, Wk, Wv, Wo, bq, bk, bv, Wp, bqkv);

    // fused QKV: N = 3*768, writes Qf/Kb/Vb in 32-wide fragment layouts
    gemm_nt<5><<<dim3(3 * F_DIM / 128, M / 128), 256, 0, stream>>>(
        xb, Wp, bqkv, Qf, M, 3 * F_DIM, F_DIM, 0.125f);

    attn_kernel<<<dim3(T_SEQ / 64, B_SZ * H_CNT), dim3(128), 0, stream>>>(Qf, Kb, Vb, Ob);

    gemm_nt<2><<<dim3(F_DIM / 128, M / 128), 256, 0, stream>>>(
        Ob, Wp + (size_t)3 * W_ELE, bo, out, M, F_DIM, F_DIM, 1.0f);
}

// Round 6
// 371.015 us; speedup vs baseline: 1.3925x; 1.3925x over previous
//
#include <hip/hip_runtime.h>
#include <cstdint>
#include <cstddef>

#define T_SEQ 2048
#define B_SZ  8
#define F_DIM 768
#define H_CNT 3
#define DH    256
#define E_ELE (T_SEQ * B_SZ * F_DIM)   // 12582912 elems per activation tensor
#define W_ELE (F_DIM * F_DIM)          // 589824 elems per weight matrix

typedef float floatx4 __attribute__((ext_vector_type(4)));
typedef short bf16x8  __attribute__((ext_vector_type(8)));

// round-half-up f32->bf16 (2 VALU); ties differ from RNE by 1 ulp (noise here)
static __device__ __forceinline__ unsigned short f2bf(float f) {
    union { float f; unsigned int i; } x; x.f = f;
    return (unsigned short)((x.i + 0x8000u) >> 16);
}
// pack two f32 -> u32 of two bf16 (lo=a, hi=b): 2 adds + v_perm
static __device__ __forceinline__ unsigned int pkbf(float a, float b) {
    union { float f; unsigned int i; } xa, xb; xa.f = a; xb.f = b;
    return __builtin_amdgcn_perm(xb.i + 0x8000u, xa.i + 0x8000u, 0x07060302u);
}
// load 8 consecutive fp32, convert to bf16x8 (packed converts)
static __device__ __forceinline__ bf16x8 cvt8(const float* __restrict__ p) {
    const floatx4 a = *(const floatx4*)p;
    const floatx4 b = *(const floatx4*)(p + 4);
    union { unsigned int u[4]; bf16x8 v; } r;
    r.u[0] = pkbf(a[0], a[1]); r.u[1] = pkbf(a[2], a[3]);
    r.u[2] = pkbf(b[0], b[1]); r.u[3] = pkbf(b[2], b[3]);
    return r.v;
}

// async global->LDS, 16B per lane; LDS dest = wave-uniform base + lane*16
#define ASYNC16(g, l) __builtin_amdgcn_global_load_lds( \
    (__attribute__((address_space(1))) void*)(void*)(g), \
    (__attribute__((address_space(3))) void*)(l), 16, 0, 0)

// ---------------------------------------------------------------------------
// Bulk fp32 -> bf16 (grid-stride over 8-elem chunks)
// ---------------------------------------------------------------------------
__global__ __launch_bounds__(256) void cvt_bf16(const float* __restrict__ src,
                                                unsigned short* __restrict__ dst,
                                                int n8)
{
    for (int i = blockIdx.x * 256 + threadIdx.x; i < n8; i += gridDim.x * 256)
        *(bf16x8*)(dst + (size_t)i * 8) = cvt8(src + (size_t)i * 8);
}

// Pack Wq|Wk|Wv|Wo -> bf16 [4*768][768]; pack bq|bk|bv -> fp32[2304].
__global__ __launch_bounds__(256) void cvt_w(
    const float* __restrict__ wq, const float* __restrict__ wk,
    const float* __restrict__ wv, const float* __restrict__ wo,
    const float* __restrict__ bq, const float* __restrict__ bk,
    const float* __restrict__ bv,
    unsigned short* __restrict__ wdst, float* __restrict__ bdst)
{
    const int y = blockIdx.y;
    const float* s = (y == 0) ? wq : (y == 1) ? wk : (y == 2) ? wv : wo;
    const int i = blockIdx.x * 256 + threadIdx.x;
    *(bf16x8*)(wdst + (size_t)y * W_ELE + (size_t)i * 8) = cvt8(s + (size_t)i * 8);
    if (y < 3 && i < F_DIM / 8) {
        const float* bs = (y == 0) ? bq : (y == 1) ? bk : bv;
        *(floatx4*)(bdst + y * F_DIM + i * 8)     = *(const floatx4*)(bs + i * 8);
        *(floatx4*)(bdst + y * F_DIM + i * 8 + 4) = *(const floatx4*)(bs + i * 8 + 4);
    }
}

// ---------------------------------------------------------------------------
// NT GEMM, both operands bf16, staged via global_load_lds w16. BK=64: half
// the per-K-step vmcnt(0)+barrier drains vs BK=32 (drain events dominate at
// K=768: 12 instead of 24). [128][64] rows are 128B stride = 16-way LDS read
// conflict, so the k-granules are XOR-swizzled: linear LDS dest + inverse-
// swizzled GLOBAL source (granule (l&7)^(l>>3)) + swizzled ds_read granule
// ((kh*4+q4)^(rr&7)) -> 2-way (free). (rule #21: both-sides-or-neither)
// C = (A[M,K] * W[N,K]^T + bias) [* scale].
// CMODE 2: C fp32 row-major.  CMODE 5: fused QKV fragment-layout scatter.
// ---------------------------------------------------------------------------
template<int CMODE>
__global__ __launch_bounds__(256, 3) void gemm_nt(
    const unsigned short* __restrict__ A,
    const unsigned short* __restrict__ W,
    const float* __restrict__ bias,
    void* __restrict__ Cv,
    int M, int N, int K, float qscale)
{
    __shared__ __align__(16) unsigned short As[128 * 64];
    __shared__ __align__(16) unsigned short Bs[128 * 64];

    const int tid  = threadIdx.x;
    const int wave = tid >> 6;
    const int lane = tid & 63;
    const int m0 = blockIdx.y * 128;
    const int n0 = blockIdx.x * 128;
    const int wm = (wave >> 1) * 64;
    const int wn = (wave & 1) * 64;
    const int q4 = lane >> 4;
    const int rr = lane & 15;

    // staging geometry: per ASYNC16 call a wave covers 8 rows x 64 elems.
    const int srow = lane >> 3;                 // row within 8-row group
    const int scol = ((lane & 7) ^ srow) * 8;   // inverse-swizzled src granule

    floatx4 acc[4][4];
#pragma unroll
    for (int i = 0; i < 4; ++i)
#pragma unroll
        for (int j = 0; j < 4; ++j) acc[i][j] = (floatx4)0.0f;

    for (int k0 = 0; k0 < K; k0 += 64) {
        __syncthreads();   // previous iteration's fragment reads complete
#pragma unroll
        for (int c = 0; c < 4; ++c) {
            const int g = wave * 4 + c;         // rowgroup 0..15
            ASYNC16(A + (size_t)(m0 + g * 8 + srow) * K + k0 + scol,
                    (unsigned short*)As + g * 512);
            ASYNC16(W + (size_t)(n0 + g * 8 + srow) * K + k0 + scol,
                    (unsigned short*)Bs + g * 512);
        }
        __syncthreads();   // staging visible (drains vmcnt)

#pragma unroll
        for (int kh = 0; kh < 2; ++kh) {
            bf16x8 af[4], bfv[4];
#pragma unroll
            for (int mt = 0; mt < 4; ++mt) {
                const int row = wm + mt * 16 + rr;
                const int pg = (kh * 4 + q4) ^ (rr & 7);   // swizzled granule
                af[mt] = *(const bf16x8*)&As[row * 64 + pg * 8];
            }
#pragma unroll
            for (int nt = 0; nt < 4; ++nt) {
                const int row = wn + nt * 16 + rr;
                const int pg = (kh * 4 + q4) ^ (rr & 7);
                bfv[nt] = *(const bf16x8*)&Bs[row * 64 + pg * 8];
            }
#pragma unroll
            for (int mt = 0; mt < 4; ++mt)
#pragma unroll
                for (int nt = 0; nt < 4; ++nt)
                    acc[mt][nt] = __builtin_amdgcn_mfma_f32_16x16x32_bf16(af[mt], bfv[nt], acc[mt][nt], 0, 0, 0);
        }
    }

#pragma unroll
    for (int nt = 0; nt < 4; ++nt) {
        const int col = n0 + wn + nt * 16 + rr;
        const float bv = bias[col];
        if (CMODE == 2) {
            float* C = (float*)Cv;
#pragma unroll
            for (int mt = 0; mt < 4; ++mt)
#pragma unroll
                for (int r = 0; r < 4; ++r) {
                    const int row = m0 + wm + mt * 16 + q4 * 4 + r;
                    C[(size_t)row * N + col] = acc[mt][nt][r] + bv;
                }
        } else {  // CMODE 5: fused QKV scatter (16-wide fragment layouts)
            const int mat = col / 768;           // wave-uniform per nt
            const int cl  = col - mat * 768;
            const int h = cl >> 8, d = cl & 255;
            const float sc = (mat == 0) ? qscale : 1.0f;
            unsigned short* base = (unsigned short*)Cv + (size_t)mat * E_ELE;
#pragma unroll
            for (int mt = 0; mt < 4; ++mt) {
#pragma unroll
                for (int r = 0; r < 4; ++r) {
                    const int row = m0 + wm + mt * 16 + q4 * 4 + r;
                    const float v = (acc[mt][nt][r] + bv) * sc;
                    const int t = row >> 3, bb = row & 7;   // row = t*B + b
                    const size_t hb = (size_t)(bb * H_CNT + h) * (T_SEQ * DH);
                    size_t idx;
                    if (mat < 2) {   // Q/K fragment layout
                        const int sblk = t >> 4, rrq = t & 15;
                        const int kc = d >> 5, q4v = (d >> 3) & 3, e = d & 7;
                        idx = hb + (size_t)(((sblk * 8 + kc) * 64 + q4v * 16 + rrq) * 8 + e);
                    } else {         // V fragment layout
                        const int skc = t >> 5, q4v = (t >> 3) & 3, e = t & 7;
                        const int dblk = d >> 4, rrq = d & 15;
                        idx = hb + (size_t)(((skc * 16 + dblk) * 64 + q4v * 16 + rrq) * 8 + e);
                    }
                    base[idx] = f2bf(v);
                }
            }
        }
    }
}

// ---------------------------------------------------------------------------
// Flash attention (R1 structure, best measured 158us): grid (T/64, B*H),
// 256 threads (4 waves), 16 Q rows/wave. Scores transposed (S^T = K Q^T);
// softmax in-reg + 2 shuffles; K/V staged via global_load_lds w16.
// ---------------------------------------------------------------------------
__global__ __launch_bounds__(256, 3) void attn_kernel(
    const unsigned short* __restrict__ Qf,
    const unsigned short* __restrict__ Kf,
    const unsigned short* __restrict__ Vf,
    unsigned short* __restrict__ Ob)
{
    __shared__ __align__(16) unsigned short Ks[8192];       // [sblk2][kc8][64][8]
    __shared__ __align__(16) unsigned short Vs[8192];       // [dblk16][64][8]
    __shared__ __align__(16) unsigned short Ps[4][16 * 40]; // per-wave P[q][s], pad 8

    const int tid  = threadIdx.x;
    const int wave = tid >> 6;
    const int lane = tid & 63;
    const int q4 = lane >> 4;
    const int rr = lane & 15;
    const int bh = blockIdx.y;
    const int b  = bh / H_CNT;
    const int h  = bh % H_CNT;
    const size_t hb = (size_t)bh * (T_SEQ * DH);

    // wave's 16 Q rows = fragment tile sb (Q prescaled by 1/8 in the GEMM)
    const int sb = blockIdx.x * 4 + wave;
    bf16x8 qf_[8];
#pragma unroll
    for (int kc = 0; kc < 8; ++kc)
        qf_[kc] = *(const bf16x8*)(Qf + hb + ((size_t)(sb * 8 + kc) * 64 + lane) * 8);

    float m_ = -1e9f, l_ = 0.0f;
    floatx4 oacc[16];
#pragma unroll
    for (int dt = 0; dt < 16; ++dt) oacc[dt] = (floatx4)0.0f;

    const int so = wave * 2048 + lane * 8;   // staging src offset (elems)
    const int sd = wave * 2048;              // staging LDS base (elems)

    for (int s0 = 0; s0 < T_SEQ; s0 += 32) {
        const unsigned short* kg = Kf + hb + (size_t)(s0 >> 4) * 4096;
        const unsigned short* vg = Vf + hb + (size_t)(s0 >> 5) * 8192;
#pragma unroll
        for (int rnd = 0; rnd < 4; ++rnd) {
            ASYNC16(kg + so + rnd * 512, (unsigned short*)Ks + sd + rnd * 512);
            ASYNC16(vg + so + rnd * 512, (unsigned short*)Vs + sd + rnd * 512);
        }
        __syncthreads();   // vmcnt drain: tiles valid

        // S^T = K Q^T : D[s][q], s-tiles smt=0,1
        floatx4 sacc[2];
        sacc[0] = (floatx4)0.0f; sacc[1] = (floatx4)0.0f;
#pragma unroll
        for (int kc = 0; kc < 8; ++kc) {
            bf16x8 k0 = *(const bf16x8*)&Ks[(kc * 64 + lane) * 8];
            bf16x8 k1 = *(const bf16x8*)&Ks[((8 + kc) * 64 + lane) * 8];
            sacc[0] = __builtin_amdgcn_mfma_f32_16x16x32_bf16(k0, qf_[kc], sacc[0], 0, 0, 0);
            sacc[1] = __builtin_amdgcn_mfma_f32_16x16x32_bf16(k1, qf_[kc], sacc[1], 0, 0, 0);
        }

        // online softmax: lane's q-col = rr; 8 s-values in regs (smt, r)
        float cm = sacc[0][0];
#pragma unroll
        for (int smt = 0; smt < 2; ++smt)
#pragma unroll
            for (int r = 0; r < 4; ++r) cm = fmaxf(cm, sacc[smt][r]);
        cm = fmaxf(cm, __shfl_xor(cm, 16));
        cm = fmaxf(cm, __shfl_xor(cm, 32));
        const float mn = fmaxf(m_, cm);
        const float alpha = __expf(m_ - mn);
        float rs = 0.0f;
#pragma unroll
        for (int smt = 0; smt < 2; ++smt)
#pragma unroll
            for (int r = 0; r < 4; ++r) {
                const float p = __expf(sacc[smt][r] - mn);
                sacc[smt][r] = p; rs += p;
            }
        rs += __shfl_xor(rs, 16);
        rs += __shfl_xor(rs, 32);
        l_ = alpha * l_ + rs;
        const int upd = (mn > m_);
        m_ = mn;

        // P (S^T C-layout) -> per-wave LDS tile P[q][s] (stride 40)
        unsigned short* pw = Ps[wave];
#pragma unroll
        for (int smt = 0; smt < 2; ++smt)
#pragma unroll
            for (int r = 0; r < 4; ++r)
                pw[rr * 40 + smt * 16 + q4 * 4 + r] = f2bf(sacc[smt][r]);
        const bf16x8 pf = *(const bf16x8*)&pw[rr * 40 + q4 * 8];

        // O rescale only when some row-max moved (wave-uniform skip)
        if (__any(upd)) {
#pragma unroll
            for (int dt = 0; dt < 16; ++dt)
#pragma unroll
                for (int r = 0; r < 4; ++r) oacc[dt][r] *= alpha;
        }

        // O^T += V^T P
#pragma unroll
        for (int dt = 0; dt < 16; ++dt) {
            bf16x8 vf = *(const bf16x8*)&Vs[(dt * 64 + lane) * 8];
            oacc[dt] = __builtin_amdgcn_mfma_f32_16x16x32_bf16(vf, pf, oacc[dt], 0, 0, 0);
        }
        __syncthreads();   // tile reads done before next chunk's staging
    }

    // epilogue: lane holds (d = dt*16 + q4*4 + r, q = rr); pack r-pairs
    const float inv_l = 1.0f / fmaxf(l_, 1e-30f);
    const int t = blockIdx.x * 64 + wave * 16 + rr;
    unsigned short* orow = Ob + (size_t)(t * B_SZ + b) * F_DIM + h * DH;
#pragma unroll
    for (int dt = 0; dt < 16; ++dt) {
#pragma unroll
        for (int rp = 0; rp < 2; ++rp) {
            const unsigned int w = pkbf(oacc[dt][rp * 2] * inv_l,
                                        oacc[dt][rp * 2 + 1] * inv_l);
            *(unsigned int*)(orow + dt * 16 + q4 * 4 + rp * 2) = w;
        }
    }
}

// ---------------------------------------------------------------------------
extern "C" void kernel_launch(void* const* d_in, const int* in_sizes, int n_in,
                              void* d_out, int out_size, void* d_ws, size_t ws_size,
                              hipStream_t stream)
{
    const float* x  = (const float*)d_in[0];
    const float* Wq = (const float*)d_in[1];
    const float* bq = (const float*)d_in[2];
    const float* Wk = (const float*)d_in[3];
    const float* bk = (const float*)d_in[4];
    const float* Wv = (const float*)d_in[5];
    const float* bv = (const float*)d_in[6];
    const float* Wo = (const float*)d_in[7];
    const float* bo = (const float*)d_in[8];
    float* out = (float*)d_out;

    const int M = T_SEQ * B_SZ;   // 16384

    // workspace: Qf | Kb | Vb | Ob(=x_bf16 before attn) | Wpack | bqkv
    unsigned short* Qf = (unsigned short*)d_ws;
    unsigned short* Kb = Qf + (size_t)E_ELE;
    unsigned short* Vb = Kb + (size_t)E_ELE;
    unsigned short* Ob = Vb + (size_t)E_ELE;      // aliases x_bf16 (dead by attn)
    unsigned short* Wp = Ob + (size_t)E_ELE;      // [Wq;Wk;Wv;Wo] bf16
    float* bqkv = (float*)(Wp + (size_t)4 * W_ELE);
    unsigned short* xb = Ob;

    cvt_bf16<<<2048, 256, 0, stream>>>(x, xb, E_ELE / 8);
    cvt_w<<<dim3(W_ELE / 8 / 256, 4), 256, 0, stream>>>(Wq, Wk, Wv, Wo, bq, bk, bv, Wp, bqkv);

    // fused QKV: N = 3*768, writes Qf/Kb/Vb in fragment layouts
    gemm_nt<5><<<dim3(3 * F_DIM / 128, M / 128), 256, 0, stream>>>(
        xb, Wp, bqkv, Qf, M, 3 * F_DIM, F_DIM, 0.125f);

    attn_kernel<<<dim3(T_SEQ / 64, B_SZ * H_CNT), dim3(256), 0, stream>>>(Qf, Kb, Vb, Ob);

    gemm_nt<2><<<dim3(F_DIM / 128, M / 128), 256, 0, stream>>>(
        Ob, Wp + (size_t)3 * W_ELE, bo, out, M, F_DIM, F_DIM, 1.0f);
}